// Round 13
// baseline (212.808 us; speedup 1.0000x reference)
//
#include <hip/hip_runtime.h>

#define FH 64
#define FW 64
#define NWF 33
#define NBIN (FH*NWF)      // 2112
#define NIMG 4096          // 4 * 32 * 32
#define PI2 6.283185307179586f

typedef unsigned short u16;
typedef unsigned int u32;
typedef __attribute__((ext_vector_type(8))) short bf16x8;
typedef __attribute__((ext_vector_type(8))) _Float16 f16x8;
typedef __attribute__((ext_vector_type(4))) unsigned short u16x4;
typedef __attribute__((ext_vector_type(4))) float f32x4;
typedef __attribute__((ext_vector_type(4))) int   i32x4;

__device__ __forceinline__ u16 f2bf(float f) {
    unsigned u = __float_as_uint(f);
    unsigned r = (u + 0x7FFFu + ((u >> 16) & 1u)) >> 16;   // RNE
    return (u16)r;
}
__device__ __forceinline__ u16 f2h(float f) {
    _Float16 h = (_Float16)f;
    return __builtin_bit_cast(u16, h);
}
__device__ __forceinline__ float2 upk(u32 v) {
    return make_float2(__uint_as_float(v << 16), __uint_as_float(v & 0xFFFF0000u));
}
__device__ __forceinline__ u32 pk(float2 v) {
    return (u32)f2bf(v.x) | ((u32)f2bf(v.y) << 16);
}
__device__ __forceinline__ f16x8 negh(f16x8 v) {
    i32x4 t = __builtin_bit_cast(i32x4, v);
    t ^= (int)0x80008000;
    return __builtin_bit_cast(f16x8, t);
}

// ---------------- forward rfft2 via MFMA-DFT: one wave/image, NO barriers, NO block init ----
// DFT twiddle fragments come from the global f16 tables CT/ST (16 KB, L2/L3-resident).
__global__ __launch_bounds__(256, 4) void fft_fwd_kernel(const float* __restrict__ x,
                                                         const u16* __restrict__ CT,
                                                         const u16* __restrict__ ST,
                                                         u32* __restrict__ Xs)
{
    __shared__ __align__(16) u16 scr[4][2][16*72];   // per-wave S^T scratch, 18432 B total

    const int tid  = threadIdx.x;
    const int lane = tid & 63;
    const int wid  = tid >> 6;
    const int a16  = lane & 15;
    const int kg   = lane >> 4;

    const int img = blockIdx.x * 4 + wid;          // qc*1024 + b*32 + ci
    const int qc = img >> 10;
    const int b  = (img >> 5) & 31;
    const int ci = img & 31;
    const float* __restrict__ src = x + ((size_t)b*128 + (size_t)qc*32 + ci) * (FH*FW);

    // A-fragments straight from global: rows h = 16mt+a16, cols w = 32ks+8kg..+7
    f16x8 xf[4][2];
    #pragma unroll
    for (int mt = 0; mt < 4; ++mt)
        #pragma unroll
        for (int ks = 0; ks < 2; ++ks) {
            const float* rp = src + (16*mt + a16)*64 + ks*32 + kg*8;
            float4 v0 = *(const float4*)rp;
            float4 v1 = *(const float4*)(rp + 4);
            xf[mt][ks] = (f16x8){ (_Float16)v0.x, (_Float16)v0.y, (_Float16)v0.z, (_Float16)v0.w,
                                  (_Float16)v1.x, (_Float16)v1.y, (_Float16)v1.z, (_Float16)v1.w };
        }

    // step2 A-twiddle frags: rows hf = 16mt2+a16 — hoisted, loaded once
    f16x8 cfa2[4][2], sfa2[4][2];
    #pragma unroll
    for (int mt2 = 0; mt2 < 4; ++mt2)
        #pragma unroll
        for (int ks = 0; ks < 2; ++ks) {
            const int rb = (16*mt2 + a16)*64 + ks*32 + kg*8;
            cfa2[mt2][ks] = *(const f16x8*)&CT[rb];
            sfa2[mt2][ks] = *(const f16x8*)&ST[rb];
        }

    u16* sre = scr[wid][0];    // [16 cols a16][72 h-stride]
    u16* sim = scr[wid][1];
    u32* __restrict__ dst = Xs + (size_t)img * NBIN;

    #pragma unroll
    for (int nt = 0; nt < 3; ++nt) {
        // ---- step1: S[h][k], k-cols = 16nt+a16; rows h via mt tiles ----
        f32x4 are[4], aim[4];
        #pragma unroll
        for (int mt = 0; mt < 4; ++mt) { are[mt] = (f32x4){0,0,0,0}; aim[mt] = (f32x4){0,0,0,0}; }
        #pragma unroll
        for (int ks = 0; ks < 2; ++ks) {
            const int rb = (16*nt + a16)*64 + ks*32 + kg*8;   // B-frag via symmetry
            f16x8 cf  = *(const f16x8*)&CT[rb];
            f16x8 nsf = negh(*(const f16x8*)&ST[rb]);
            #pragma unroll
            for (int mt = 0; mt < 4; ++mt) {
                are[mt] = __builtin_amdgcn_mfma_f32_16x16x32_f16(xf[mt][ks], cf,  are[mt], 0, 0, 0);
                aim[mt] = __builtin_amdgcn_mfma_f32_16x16x32_f16(xf[mt][ks], nsf, aim[mt], 0, 0, 0);
            }
        }
        // ---- scratch: S^T per column a16 (D rows h = 16mt+4kg+r) ----
        #pragma unroll
        for (int mt = 0; mt < 4; ++mt) {
            u16x4 re4 = { f2h(are[mt][0]), f2h(are[mt][1]), f2h(are[mt][2]), f2h(are[mt][3]) };
            u16x4 im4 = { f2h(aim[mt][0]), f2h(aim[mt][1]), f2h(aim[mt][2]), f2h(aim[mt][3]) };
            *(u16x4*)&sre[a16*72 + 16*mt + 4*kg] = re4;
            *(u16x4*)&sim[a16*72 + 16*mt + 4*kg] = im4;
        }
        // same-wave read-back (lgkmcnt-ordered; no barrier needed)
        f16x8 br[2], bi[2];
        #pragma unroll
        for (int ks = 0; ks < 2; ++ks) {
            br[ks] = *(const f16x8*)&sre[a16*72 + ks*32 + kg*8];
            bi[ks] = *(const f16x8*)&sim[a16*72 + ks*32 + kg*8];
        }
        // ---- step2: X[hf][k] = (C - iS)*S, k = 16nt+a16 ----
        const int k = 16*nt + a16;
        #pragma unroll
        for (int mt2 = 0; mt2 < 4; ++mt2) {
            f32x4 xre = (f32x4){0,0,0,0}, xim = (f32x4){0,0,0,0};
            #pragma unroll
            for (int ks = 0; ks < 2; ++ks) {
                xre = __builtin_amdgcn_mfma_f32_16x16x32_f16(cfa2[mt2][ks], br[ks], xre, 0, 0, 0);
                xre = __builtin_amdgcn_mfma_f32_16x16x32_f16(sfa2[mt2][ks], bi[ks], xre, 0, 0, 0);
                xim = __builtin_amdgcn_mfma_f32_16x16x32_f16(cfa2[mt2][ks], bi[ks], xim, 0, 0, 0);
                xim = __builtin_amdgcn_mfma_f32_16x16x32_f16(negh(sfa2[mt2][ks]), br[ks], xim, 0, 0, 0);
            }
            if (k < 33) {
                #pragma unroll
                for (int r = 0; r < 4; ++r)
                    dst[(16*mt2 + 4*kg + r)*33 + k] = pk(make_float2(xre[r], xim[r]));
            }
        }
    }
}

// ---------------- transpose X: [img][bin] u32 -> [bin][q][ri][b][i] bf16 ----------------
__global__ __launch_bounds__(256) void xpose_x_kernel(const u32* __restrict__ Xs,
                                                      u32* __restrict__ XT)
{
    const int g    = blockIdx.x;        // q*32 + b
    const int bin0 = blockIdx.y * 32;
    __shared__ u32 tile[32][33];
    const int tid = threadIdx.x;
    #pragma unroll
    for (int it = 0; it < 4; ++it) {
        int e = tid + it*256;
        int imgL = e >> 5, binL = e & 31;
        tile[imgL][binL] = Xs[(size_t)(g*32 + imgL) * NBIN + bin0 + binL];
    }
    __syncthreads();
    const int q = g >> 5, b = g & 31;
    #pragma unroll
    for (int it = 0; it < 2; ++it) {
        int e = tid + it*256;          // 512 tasks: [binL][i-pair]
        int binL = e >> 4, pr = e & 15;
        u32 v0 = tile[pr*2][binL], v1 = tile[pr*2 + 1][binL];
        u32 re = (v0 & 0xFFFFu) | (v1 << 16);
        u32 im = (v0 >> 16) | (v1 & 0xFFFF0000u);
        size_t base = ((size_t)(bin0 + binL)*8 + q*2) * 512 + b*16 + pr;  // u32 units
        XT[base]       = re;
        XT[base + 512] = im;
    }
}

// ---------------- transpose W (tiled) + one table-gen block row ----------------
__global__ __launch_bounds__(256) void prep_w_kernel(
    const float* __restrict__ s0, const float* __restrict__ s1,
    const float* __restrict__ s2, const float* __restrict__ s3,
    const float* __restrict__ s4, const float* __restrict__ s5,
    const float* __restrict__ s6, const float* __restrict__ s7,
    u16* __restrict__ WT, u16* __restrict__ TBL)
{
    if (blockIdx.y == 32) {
        // DFT tables: CT[a*64+b]=cos(2pi ab/64), ST=sin (f16), 16 KB total
        if (blockIdx.x == 0) {
            for (int e = threadIdx.x; e < 4096; e += 256) {
                int a = e >> 6, bb = e & 63;
                float sn, cs;
                __sincosf(PI2 * (float)((a*bb) & 63) * (1.f/64.f), &sn, &cs);
                TBL[e]        = f2h(cs);
                TBL[4096 + e] = f2h(sn);
            }
        }
        return;
    }
    const int bt = blockIdx.x;          // 66 bin tiles of 32
    const int a  = blockIdx.y >> 2;     // array 0..7 (kr_wxyz, ki_wxyz)
    const int o0 = (blockIdx.y & 3) * 8;
    const float* __restrict__ src =
        (a==0)?s0:(a==1)?s1:(a==2)?s2:(a==3)?s3:(a==4)?s4:(a==5)?s5:(a==6)?s6:s7;
    const int bin0 = bt * 32;
    __shared__ u16 lds2[32*264];        // [binL][chL], chL = oo*32 + i
    const int tid = threadIdx.x;

    #pragma unroll
    for (int it = 0; it < 8; ++it) {
        int e = tid + it*256;           // 2048 float4 tasks
        int f4 = e & 7, rt = e >> 3;
        int i = rt & 31, oo = rt >> 5;
        int io = i*32 + o0 + oo;
        float4 v = ((const float4*)src)[(size_t)io*(NBIN/4) + bt*8 + f4];
        int chL = oo*32 + i;
        int bb = f4*4;
        lds2[(bb+0)*264 + chL] = f2bf(v.x);
        lds2[(bb+1)*264 + chL] = f2bf(v.y);
        lds2[(bb+2)*264 + chL] = f2bf(v.z);
        lds2[(bb+3)*264 + chL] = f2bf(v.w);
    }
    __syncthreads();
    const int p = a & 3, ri = a >> 2;
    #pragma unroll
    for (int it = 0; it < 4; ++it) {
        int e = tid + it*256;           // 1024 bf16x8 tasks
        int binL = e >> 5, c8 = e & 31;
        bf16x8 v = *(const bf16x8*)&lds2[binL*264 + c8*8];
        size_t d = ((size_t)(bin0 + binL)*8 + p*2 + ri)*1024 + o0*32 + c8*8;
        *(bf16x8*)(WT + d) = v;
    }
}

// ---------------- per-bin quaternion contraction via MFMA ----------------
__global__ __launch_bounds__(256) void contract_kernel(
    const u16* __restrict__ XT, const u16* __restrict__ WT,
    u32* __restrict__ P)
{
    const int bid  = blockIdx.x;
    const int bin  = (bid & 7) * (NBIN/8) + (bid >> 3);   // chunked XCD swizzle
    const int wid  = threadIdx.x >> 6;
    const int lane = threadIdx.x & 63;
    const int bh = wid >> 1, oh = wid & 1;
    const int row = lane & 15, kg = lane >> 4;

    const u16* __restrict__ xb = XT + (size_t)bin * 8192;
    const u16* __restrict__ wb = WT + (size_t)bin * 8192;

    bf16x8 ax[4][2];
    #pragma unroll
    for (int q = 0; q < 4; ++q)
        #pragma unroll
        for (int ri = 0; ri < 2; ++ri)
            ax[q][ri] = *(const bf16x8*)(xb + ((q*2 + ri)*32 + bh*16 + row)*32 + kg*8);

    bf16x8 wpos[4][2], wneg[4][2];
    #pragma unroll
    for (int p = 0; p < 4; ++p)
        #pragma unroll
        for (int ri = 0; ri < 2; ++ri) {
            bf16x8 w = *(const bf16x8*)(wb + ((p*2 + ri)*32 + oh*16 + row)*32 + kg*8);
            wpos[p][ri] = w;
            i32x4 t = __builtin_bit_cast(i32x4, w);
            t ^= (int)0x80008000;
            wneg[p][ri] = __builtin_bit_cast(bf16x8, t);
        }

    f32x4 acc[4][2];
    #pragma unroll
    for (int c = 0; c < 4; ++c)
        #pragma unroll
        for (int ri = 0; ri < 2; ++ri)
            acc[c][ri] = (f32x4){0.f, 0.f, 0.f, 0.f};

    constexpr int PI_[4][4] = {{0,1,2,3},{1,0,3,2},{2,3,0,1},{3,2,1,0}};
    constexpr int SG_[4][4] = {{1,-1,-1,-1},{1,1,-1,1},{1,1,1,-1},{1,-1,1,1}};
    #pragma unroll
    for (int c = 0; c < 4; ++c)
        #pragma unroll
        for (int q = 0; q < 4; ++q) {
            const int  p   = PI_[c][q];
            const bool pos = SG_[c][q] > 0;
            bf16x8 wr_s = pos ? wpos[p][0] : wneg[p][0];
            bf16x8 wi_s = pos ? wpos[p][1] : wneg[p][1];
            bf16x8 wi_m = pos ? wneg[p][1] : wpos[p][1];
            acc[c][0] = __builtin_amdgcn_mfma_f32_16x16x32_bf16(ax[q][0], wr_s, acc[c][0], 0, 0, 0);
            acc[c][0] = __builtin_amdgcn_mfma_f32_16x16x32_bf16(ax[q][1], wi_m, acc[c][0], 0, 0, 0);
            acc[c][1] = __builtin_amdgcn_mfma_f32_16x16x32_bf16(ax[q][1], wr_s, acc[c][1], 0, 0, 0);
            acc[c][1] = __builtin_amdgcn_mfma_f32_16x16x32_bf16(ax[q][0], wi_s, acc[c][1], 0, 0, 0);
        }

    u32* __restrict__ dst = P + (size_t)bin * 4096;
    #pragma unroll
    for (int c = 0; c < 4; ++c)
        #pragma unroll
        for (int r = 0; r < 4; ++r) {
            int b_ = bh*16 + kg*4 + r;
            int o  = oh*16 + row;
            dst[c*1024 + b_*32 + o] = pk(make_float2(acc[c][0][r], acc[c][1][r]));
        }
}

// ---------------- transpose P: [bin][img] u32 -> PT[img][bin] u32 ----------------
__global__ __launch_bounds__(256) void pxpose_kernel(const u32* __restrict__ P,
                                                     u32* __restrict__ PT)
{
    const int bin0 = blockIdx.x * 32;
    const int img0 = blockIdx.y * 32;
    __shared__ u32 tile[32][33];
    const int tid = threadIdx.x;
    #pragma unroll
    for (int it = 0; it < 4; ++it) {
        int e = tid + it*256;
        int bi = e >> 5, im = e & 31;
        tile[bi][im] = P[(size_t)(bin0 + bi) * 4096 + img0 + im];
    }
    __syncthreads();
    #pragma unroll
    for (int it = 0; it < 4; ++it) {
        int e = tid + it*256;
        int im = e >> 5, bi = e & 31;
        PT[(size_t)(img0 + im) * NBIN + bin0 + bi] = tile[bi][im];
    }
}

// ---------------- inverse rfft2 via MFMA-DFT: TWO waves per image, global tables ------------
__global__ __launch_bounds__(512, 4) void fft_inv_kernel(const u32* __restrict__ PT,
                                                         const u16* __restrict__ CT,
                                                         const u16* __restrict__ ST,
                                                         float* __restrict__ out)
{
    __shared__ __align__(16) u16 wbuf[4][7168];    // per-image: ET (2x48x72) / T (2x64x56)

    const int tid  = threadIdx.x;
    const int lane = tid & 63;
    const int wid  = tid >> 6;
    const int slot = wid >> 1;
    const int half = wid & 1;
    const int ltid = (half << 6) | lane;
    const int a16  = lane & 15;
    const int q    = lane >> 4;

    const int img = blockIdx.x * 4 + slot;         // c*1024 + b*32 + oc
    const int c  = img >> 10;
    const int b  = (img >> 5) & 31;
    const int oc = img & 31;

    // stage E^T: ETre[k][hf], ETim[k][hf], stride 72. Rows k=33..47 MUST be zero.
    u16* ETre = wbuf[slot];
    u16* ETim = wbuf[slot] + 48*72;
    for (int j = 33*72 + ltid; j < 48*72; j += 128) {
        ETre[j] = 0;
        ETim[j] = 0;
    }
    const u32* __restrict__ srcP = PT + (size_t)img * NBIN;
    for (int i = 0; i < 17; ++i) {
        int t = i*128 + ltid;
        if (t < NBIN) {
            int hf = t / 33, k = t - hf*33;
            float2 v = upk(srcP[t]);
            ETre[k*72 + hf] = f2h(v.x);
            ETim[k*72 + hf] = f2h(v.y);
        }
    }
    __syncthreads();

    // preload this wave's E^T A-fragments (mt = 2*half + mtl, valid mt < 3)
    f16x8 ere[2][2], eim[2][2];
    #pragma unroll
    for (int mtl = 0; mtl < 2; ++mtl) {
        const int mt = 2*half + mtl;
        if (mt < 3) {
            #pragma unroll
            for (int ks = 0; ks < 2; ++ks) {
                ere[mtl][ks] = *(const f16x8*)&ETre[(16*mt + a16)*72 + ks*32 + q*8];
                eim[mtl][ks] = *(const f16x8*)&ETim[(16*mt + a16)*72 + ks*32 + q*8];
            }
        }
    }
    __syncthreads();

    // step1: T_re^T = Ere*C - Eim*S ; T_im^T = Ere*S + Eim*C; D-layout writes T[h][m]
    u16* Tre = wbuf[slot];             // [64][56]
    u16* Tim = wbuf[slot] + 64*56;
    #pragma unroll
    for (int mtl = 0; mtl < 2; ++mtl) {
        const int mt = 2*half + mtl;
        if (mt < 3) {
            #pragma unroll
            for (int nt = 0; nt < 4; ++nt) {
                f32x4 tre = (f32x4){0,0,0,0}, tim = (f32x4){0,0,0,0};
                #pragma unroll
                for (int ks = 0; ks < 2; ++ks) {
                    const int rb = (16*nt + a16)*64 + ks*32 + q*8;
                    f16x8 cf = *(const f16x8*)&CT[rb];
                    f16x8 sf = *(const f16x8*)&ST[rb];
                    tre = __builtin_amdgcn_mfma_f32_16x16x32_f16(ere[mtl][ks], cf, tre, 0, 0, 0);
                    tre = __builtin_amdgcn_mfma_f32_16x16x32_f16(eim[mtl][ks], negh(sf), tre, 0, 0, 0);
                    tim = __builtin_amdgcn_mfma_f32_16x16x32_f16(ere[mtl][ks], sf, tim, 0, 0, 0);
                    tim = __builtin_amdgcn_mfma_f32_16x16x32_f16(eim[mtl][ks], cf, tim, 0, 0, 0);
                }
                const int m0 = 16*mt + 4*q;        // row = m, col = h
                u16x4 r4, i4;
                #pragma unroll
                for (int r = 0; r < 4; ++r) {
                    int m = m0 + r;
                    float s = (m == 0 || m == 32) ? (1.f/4096.f) : (2.f/4096.f);
                    r4[r] = (m < 33) ? f2h(tre[r] * s) : (u16)0;
                    i4[r] = (m < 33) ? f2h(tim[r] * s) : (u16)0;
                }
                *(u16x4*)&Tre[(16*nt + a16)*56 + m0] = r4;
                *(u16x4*)&Tim[(16*nt + a16)*56 + m0] = i4;
            }
        }
    }
    __syncthreads();

    // step2: out[h][w] = sum_m Tre[h][m]*C[w][m] - Tim[h][m]*S[w][m]
    float* __restrict__ dst = out + ((size_t)b*128 + (size_t)c*32 + oc) * (FH*FW);
    #pragma unroll
    for (int mtl = 0; mtl < 2; ++mtl) {
        const int mt = 2*half + mtl;
        f16x8 tfr[2], tfi[2];
        #pragma unroll
        for (int ks = 0; ks < 2; ++ks) {
            const int mbase = ks*32 + q*8;
            if (mbase < 48) {
                tfr[ks] = *(const f16x8*)&Tre[(16*mt + a16)*56 + mbase];
                tfi[ks] = *(const f16x8*)&Tim[(16*mt + a16)*56 + mbase];
            } else {
                tfr[ks] = (f16x8){0,0,0,0,0,0,0,0};
                tfi[ks] = (f16x8){0,0,0,0,0,0,0,0};
            }
        }
        #pragma unroll
        for (int nt = 0; nt < 4; ++nt) {
            f32x4 acc = (f32x4){0,0,0,0};
            #pragma unroll
            for (int ks = 0; ks < 2; ++ks) {
                const int rb = (16*nt + a16)*64 + ks*32 + q*8;
                f16x8 cf = *(const f16x8*)&CT[rb];
                f16x8 sf = *(const f16x8*)&ST[rb];
                acc = __builtin_amdgcn_mfma_f32_16x16x32_f16(tfr[ks], cf, acc, 0, 0, 0);
                acc = __builtin_amdgcn_mfma_f32_16x16x32_f16(tfi[ks], negh(sf), acc, 0, 0, 0);
            }
            // col = w = 16nt+a16, row = h = 16mt+4q+r
            #pragma unroll
            for (int r = 0; r < 4; ++r)
                dst[(16*mt + 4*q + r)*64 + 16*nt + a16] = acc[r];
        }
    }
}

extern "C" void kernel_launch(void* const* d_in, const int* in_sizes, int n_in,
                              void* d_out, int out_size, void* d_ws, size_t ws_size,
                              hipStream_t stream)
{
    const float* x   = (const float*)d_in[0];
    const float* krw = (const float*)d_in[1];
    const float* krx = (const float*)d_in[2];
    const float* kry = (const float*)d_in[3];
    const float* krz = (const float*)d_in[4];
    const float* kiw = (const float*)d_in[5];
    const float* kix = (const float*)d_in[6];
    const float* kiy = (const float*)d_in[7];
    const float* kiz = (const float*)d_in[8];

    // ws regions (34.6 MB each): [XT / PT] [WT] [Xs / P] [TBL 16 KB]
    const size_t R = (size_t)NBIN * 8192 * sizeof(u16);   // 34.6 MB
    u16* XT = (u16*)d_ws;
    u32* PT = (u32*)d_ws;                                  // alias: XT dead after contract
    u16* WT = (u16*)((char*)d_ws + R);
    u32* Xs = (u32*)((char*)d_ws + 2*R);
    u32* P  = Xs;                                          // alias: Xs dead after xpose
    u16* TBL = (u16*)((char*)d_ws + 3*R);                  // CT[4096] | ST[4096] f16
    u16* CTt = TBL;
    u16* STt = TBL + 4096;
    float* out = (float*)d_out;

    prep_w_kernel<<<dim3(66, 33), 256, 0, stream>>>(krw, krx, kry, krz,
                                                    kiw, kix, kiy, kiz, WT, TBL);
    fft_fwd_kernel<<<dim3(NIMG/4), 256, 0, stream>>>(x, CTt, STt, Xs);
    xpose_x_kernel<<<dim3(128, NBIN/32), 256, 0, stream>>>(Xs, (u32*)XT);
    contract_kernel<<<dim3(NBIN), 256, 0, stream>>>(XT, WT, P);
    pxpose_kernel<<<dim3(NBIN/32, NIMG/32), 256, 0, stream>>>(P, PT);
    fft_inv_kernel<<<dim3(NIMG/4), 512, 0, stream>>>(PT, CTt, STt, out);
}

// Round 14
// 117.582 us; speedup vs baseline: 1.8099x; 1.8099x over previous
//
#include <hip/hip_runtime.h>

#define FH 64
#define FW 64
#define NWF 33
#define NBIN (FH*NWF)      // 2112
#define NIMG 4096          // 4 * 32 * 32
#define PI2 6.283185307179586f

typedef unsigned short u16;
typedef unsigned int u32;
typedef __attribute__((ext_vector_type(8))) short bf16x8;
typedef __attribute__((ext_vector_type(8))) _Float16 f16x8;
typedef __attribute__((ext_vector_type(4))) unsigned short u16x4;
typedef __attribute__((ext_vector_type(4))) float f32x4;
typedef __attribute__((ext_vector_type(4))) int   i32x4;

__device__ __forceinline__ u16 f2bf(float f) {
    unsigned u = __float_as_uint(f);
    unsigned r = (u + 0x7FFFu + ((u >> 16) & 1u)) >> 16;   // RNE
    return (u16)r;
}
__device__ __forceinline__ u16 f2h(float f) {
    _Float16 h = (_Float16)f;
    return __builtin_bit_cast(u16, h);
}
__device__ __forceinline__ float2 upk(u32 v) {
    return make_float2(__uint_as_float(v << 16), __uint_as_float(v & 0xFFFF0000u));
}
__device__ __forceinline__ u32 pk(float2 v) {
    return (u32)f2bf(v.x) | ((u32)f2bf(v.y) << 16);
}
__device__ __forceinline__ f16x8 negh(f16x8 v) {
    i32x4 t = __builtin_bit_cast(i32x4, v);
    t ^= (int)0x80008000;
    return __builtin_bit_cast(f16x8, t);
}

// ========== FAT KERNEL: fft_fwd (blocks 0..1023) ∥ prep_w (blocks 1024..3135) ==========
// Arena 36864 B -> 4 blocks/CU for BOTH paths (fixes r11's occupancy tax on prep_w).
// fwd path = round-12 body verbatim: mats(18432B) + per-wave scratch(18432B), one barrier,
// no hoisted twiddle fragments (r13 lesson: hoisting spilled to scratch).
__global__ __launch_bounds__(256, 4) void fwd_prep_kernel(
    const float* __restrict__ x, u32* __restrict__ Xs,
    const float* __restrict__ s0, const float* __restrict__ s1,
    const float* __restrict__ s2, const float* __restrict__ s3,
    const float* __restrict__ s4, const float* __restrict__ s5,
    const float* __restrict__ s6, const float* __restrict__ s7,
    u16* __restrict__ WT)
{
    __shared__ __align__(16) u16 sm[18432];   // 36864 B
    const int tid = threadIdx.x;

    if (blockIdx.x < 1024) {
        // ---------------- forward rfft2 via MFMA-DFT: one wave/image, barrier-free ----------
        const int lane = tid & 63;
        const int wid  = tid >> 6;
        const int a16  = lane & 15;
        const int kg   = lane >> 4;

        u16* mats0 = sm;                 // cos[a*72+b], symmetric
        u16* mats1 = sm + 4608;          // sin[a*72+b]
        u16* sre   = sm + 9216 + wid*2304;
        u16* sim   = sre + 1152;

        for (int t = tid; t < 4096; t += 256) {
            int a = t >> 6, bb = t & 63;
            float sn, cs;
            __sincosf(PI2 * (float)((a*bb) & 63) * (1.f/64.f), &sn, &cs);
            mats0[a*72 + bb] = f2h(cs);
            mats1[a*72 + bb] = f2h(sn);
        }
        __syncthreads();   // the only barrier

        const int img = blockIdx.x * 4 + wid;          // qc*1024 + b*32 + ci
        const int qc = img >> 10;
        const int b  = (img >> 5) & 31;
        const int ci = img & 31;
        const float* __restrict__ src = x + ((size_t)b*128 + (size_t)qc*32 + ci) * (FH*FW);

        // A-fragments straight from global: rows h = 16mt+a16, cols w = 32ks+8kg..+7
        f16x8 xf[4][2];
        #pragma unroll
        for (int mt = 0; mt < 4; ++mt)
            #pragma unroll
            for (int ks = 0; ks < 2; ++ks) {
                const float* rp = src + (16*mt + a16)*64 + ks*32 + kg*8;
                float4 v0 = *(const float4*)rp;
                float4 v1 = *(const float4*)(rp + 4);
                xf[mt][ks] = (f16x8){ (_Float16)v0.x, (_Float16)v0.y, (_Float16)v0.z, (_Float16)v0.w,
                                      (_Float16)v1.x, (_Float16)v1.y, (_Float16)v1.z, (_Float16)v1.w };
            }

        u32* __restrict__ dst = Xs + (size_t)img * NBIN;

        #pragma unroll
        for (int nt = 0; nt < 3; ++nt) {
            // ---- step1: S[h][k], k-cols = 16nt+a16 ----
            f32x4 are[4], aim[4];
            #pragma unroll
            for (int mt = 0; mt < 4; ++mt) { are[mt] = (f32x4){0,0,0,0}; aim[mt] = (f32x4){0,0,0,0}; }
            #pragma unroll
            for (int ks = 0; ks < 2; ++ks) {
                const int rb = (16*nt + a16)*72 + ks*32 + kg*8;   // B-frag via symmetry
                f16x8 cf  = *(const f16x8*)&mats0[rb];
                f16x8 nsf = negh(*(const f16x8*)&mats1[rb]);
                #pragma unroll
                for (int mt = 0; mt < 4; ++mt) {
                    are[mt] = __builtin_amdgcn_mfma_f32_16x16x32_f16(xf[mt][ks], cf,  are[mt], 0, 0, 0);
                    aim[mt] = __builtin_amdgcn_mfma_f32_16x16x32_f16(xf[mt][ks], nsf, aim[mt], 0, 0, 0);
                }
            }
            // ---- scratch: S^T per column a16 (D rows h = 16mt+4kg+r) ----
            #pragma unroll
            for (int mt = 0; mt < 4; ++mt) {
                u16x4 re4 = { f2h(are[mt][0]), f2h(are[mt][1]), f2h(are[mt][2]), f2h(are[mt][3]) };
                u16x4 im4 = { f2h(aim[mt][0]), f2h(aim[mt][1]), f2h(aim[mt][2]), f2h(aim[mt][3]) };
                *(u16x4*)&sre[a16*72 + 16*mt + 4*kg] = re4;
                *(u16x4*)&sim[a16*72 + 16*mt + 4*kg] = im4;
            }
            // same-wave read-back (lgkmcnt-ordered; no barrier needed)
            f16x8 br[2], bi[2];
            #pragma unroll
            for (int ks = 0; ks < 2; ++ks) {
                br[ks] = *(const f16x8*)&sre[a16*72 + ks*32 + kg*8];
                bi[ks] = *(const f16x8*)&sim[a16*72 + ks*32 + kg*8];
            }
            // ---- step2: X[hf][k] = (C - iS)*S, k = 16nt+a16 ----
            const int k = 16*nt + a16;
            #pragma unroll
            for (int mt2 = 0; mt2 < 4; ++mt2) {
                f32x4 xre = (f32x4){0,0,0,0}, xim = (f32x4){0,0,0,0};
                #pragma unroll
                for (int ks = 0; ks < 2; ++ks) {
                    const int rb = (16*mt2 + a16)*72 + ks*32 + kg*8;  // A-frag rows hf
                    f16x8 cf = *(const f16x8*)&mats0[rb];
                    f16x8 sf = *(const f16x8*)&mats1[rb];
                    xre = __builtin_amdgcn_mfma_f32_16x16x32_f16(cf, br[ks], xre, 0, 0, 0);
                    xre = __builtin_amdgcn_mfma_f32_16x16x32_f16(sf, bi[ks], xre, 0, 0, 0);
                    xim = __builtin_amdgcn_mfma_f32_16x16x32_f16(cf, bi[ks], xim, 0, 0, 0);
                    xim = __builtin_amdgcn_mfma_f32_16x16x32_f16(negh(sf), br[ks], xim, 0, 0, 0);
                }
                if (k < 33) {
                    #pragma unroll
                    for (int r = 0; r < 4; ++r)
                        dst[(16*mt2 + 4*kg + r)*33 + k] = pk(make_float2(xre[r], xim[r]));
                }
            }
        }
    } else {
        // ---------------- transpose W (tiled): [i][o][bin] f32 -> [bin][p][ri][o][i] bf16 ------
        const int pb = blockIdx.x - 1024;   // 0..2111
        const int bt = pb % 66;             // bin tile
        const int ay = pb / 66;             // 0..31
        const int a  = ay >> 2;             // array 0..7 (kr_wxyz, ki_wxyz)
        const int o0 = (ay & 3) * 8;
        const float* __restrict__ src =
            (a==0)?s0:(a==1)?s1:(a==2)?s2:(a==3)?s3:(a==4)?s4:(a==5)?s5:(a==6)?s6:s7;
        const int bin0 = bt * 32;
        u16* lds2 = sm;                     // [binL][chL], stride 264, 16896 B

        #pragma unroll
        for (int it = 0; it < 8; ++it) {
            int e = tid + it*256;           // 2048 float4 tasks
            int f4 = e & 7, rt = e >> 3;
            int i = rt & 31, oo = rt >> 5;
            int io = i*32 + o0 + oo;
            float4 v = ((const float4*)src)[(size_t)io*(NBIN/4) + bt*8 + f4];
            int chL = oo*32 + i;
            int bb = f4*4;
            lds2[(bb+0)*264 + chL] = f2bf(v.x);
            lds2[(bb+1)*264 + chL] = f2bf(v.y);
            lds2[(bb+2)*264 + chL] = f2bf(v.z);
            lds2[(bb+3)*264 + chL] = f2bf(v.w);
        }
        __syncthreads();
        const int p = a & 3, ri = a >> 2;
        #pragma unroll
        for (int it = 0; it < 4; ++it) {
            int e = tid + it*256;           // 1024 bf16x8 tasks
            int binL = e >> 5, c8 = e & 31;
            bf16x8 v = *(const bf16x8*)&lds2[binL*264 + c8*8];
            size_t d = ((size_t)(bin0 + binL)*8 + p*2 + ri)*1024 + o0*32 + c8*8;
            *(bf16x8*)(WT + d) = v;
        }
    }
}

// ---------------- transpose X: [img][bin] u32 -> [bin][q][ri][b][i] bf16 ----------------
__global__ __launch_bounds__(256) void xpose_x_kernel(const u32* __restrict__ Xs,
                                                      u32* __restrict__ XT)
{
    const int g    = blockIdx.x;        // q*32 + b
    const int bin0 = blockIdx.y * 32;
    __shared__ u32 tile[32][33];
    const int tid = threadIdx.x;
    #pragma unroll
    for (int it = 0; it < 4; ++it) {
        int e = tid + it*256;
        int imgL = e >> 5, binL = e & 31;
        tile[imgL][binL] = Xs[(size_t)(g*32 + imgL) * NBIN + bin0 + binL];
    }
    __syncthreads();
    const int q = g >> 5, b = g & 31;
    #pragma unroll
    for (int it = 0; it < 2; ++it) {
        int e = tid + it*256;          // 512 tasks: [binL][i-pair]
        int binL = e >> 4, pr = e & 15;
        u32 v0 = tile[pr*2][binL], v1 = tile[pr*2 + 1][binL];
        u32 re = (v0 & 0xFFFFu) | (v1 << 16);
        u32 im = (v0 >> 16) | (v1 & 0xFFFF0000u);
        size_t base = ((size_t)(bin0 + binL)*8 + q*2) * 512 + b*16 + pr;  // u32 units
        XT[base]       = re;
        XT[base + 512] = im;
    }
}

// ---------------- per-bin quaternion contraction via MFMA ----------------
__global__ __launch_bounds__(256) void contract_kernel(
    const u16* __restrict__ XT, const u16* __restrict__ WT,
    u32* __restrict__ P)
{
    const int bid  = blockIdx.x;
    const int bin  = (bid & 7) * (NBIN/8) + (bid >> 3);   // chunked XCD swizzle
    const int wid  = threadIdx.x >> 6;
    const int lane = threadIdx.x & 63;
    const int bh = wid >> 1, oh = wid & 1;
    const int row = lane & 15, kg = lane >> 4;

    const u16* __restrict__ xb = XT + (size_t)bin * 8192;
    const u16* __restrict__ wb = WT + (size_t)bin * 8192;

    bf16x8 ax[4][2];
    #pragma unroll
    for (int q = 0; q < 4; ++q)
        #pragma unroll
        for (int ri = 0; ri < 2; ++ri)
            ax[q][ri] = *(const bf16x8*)(xb + ((q*2 + ri)*32 + bh*16 + row)*32 + kg*8);

    bf16x8 wpos[4][2], wneg[4][2];
    #pragma unroll
    for (int p = 0; p < 4; ++p)
        #pragma unroll
        for (int ri = 0; ri < 2; ++ri) {
            bf16x8 w = *(const bf16x8*)(wb + ((p*2 + ri)*32 + oh*16 + row)*32 + kg*8);
            wpos[p][ri] = w;
            i32x4 t = __builtin_bit_cast(i32x4, w);
            t ^= (int)0x80008000;
            wneg[p][ri] = __builtin_bit_cast(bf16x8, t);
        }

    f32x4 acc[4][2];
    #pragma unroll
    for (int c = 0; c < 4; ++c)
        #pragma unroll
        for (int ri = 0; ri < 2; ++ri)
            acc[c][ri] = (f32x4){0.f, 0.f, 0.f, 0.f};

    constexpr int PI_[4][4] = {{0,1,2,3},{1,0,3,2},{2,3,0,1},{3,2,1,0}};
    constexpr int SG_[4][4] = {{1,-1,-1,-1},{1,1,-1,1},{1,1,1,-1},{1,-1,1,1}};
    #pragma unroll
    for (int c = 0; c < 4; ++c)
        #pragma unroll
        for (int q = 0; q < 4; ++q) {
            const int  p   = PI_[c][q];
            const bool pos = SG_[c][q] > 0;
            bf16x8 wr_s = pos ? wpos[p][0] : wneg[p][0];
            bf16x8 wi_s = pos ? wpos[p][1] : wneg[p][1];
            bf16x8 wi_m = pos ? wneg[p][1] : wpos[p][1];
            acc[c][0] = __builtin_amdgcn_mfma_f32_16x16x32_bf16(ax[q][0], wr_s, acc[c][0], 0, 0, 0);
            acc[c][0] = __builtin_amdgcn_mfma_f32_16x16x32_bf16(ax[q][1], wi_m, acc[c][0], 0, 0, 0);
            acc[c][1] = __builtin_amdgcn_mfma_f32_16x16x32_bf16(ax[q][1], wr_s, acc[c][1], 0, 0, 0);
            acc[c][1] = __builtin_amdgcn_mfma_f32_16x16x32_bf16(ax[q][0], wi_s, acc[c][1], 0, 0, 0);
        }

    u32* __restrict__ dst = P + (size_t)bin * 4096;
    #pragma unroll
    for (int c = 0; c < 4; ++c)
        #pragma unroll
        for (int r = 0; r < 4; ++r) {
            int b_ = bh*16 + kg*4 + r;
            int o  = oh*16 + row;
            dst[c*1024 + b_*32 + o] = pk(make_float2(acc[c][0][r], acc[c][1][r]));
        }
}

// ---------------- transpose P: [bin][img] u32 -> PT[img][bin] u32 ----------------
__global__ __launch_bounds__(256) void pxpose_kernel(const u32* __restrict__ P,
                                                     u32* __restrict__ PT)
{
    const int bin0 = blockIdx.x * 32;
    const int img0 = blockIdx.y * 32;
    __shared__ u32 tile[32][33];
    const int tid = threadIdx.x;
    #pragma unroll
    for (int it = 0; it < 4; ++it) {
        int e = tid + it*256;
        int bi = e >> 5, im = e & 31;
        tile[bi][im] = P[(size_t)(bin0 + bi) * 4096 + img0 + im];
    }
    __syncthreads();
    #pragma unroll
    for (int it = 0; it < 4; ++it) {
        int e = tid + it*256;
        int im = e >> 5, bi = e & 31;
        PT[(size_t)(img0 + im) * NBIN + bin0 + bi] = tile[bi][im];
    }
}

// ---------------- inverse rfft2 via MFMA-DFT: TWO waves per image ----------------
__global__ __launch_bounds__(512, 4) void fft_inv_kernel(const u32* __restrict__ PT,
                                                         float* __restrict__ out)
{
    __shared__ __align__(16) u16 mats[2][64*72];   // cos/sin(+2pi ab/64), symmetric
    __shared__ __align__(16) u16 wbuf[4][7168];    // per-image: ET (2x48x72) / T (2x64x56)

    const int tid  = threadIdx.x;
    const int lane = tid & 63;
    const int wid  = tid >> 6;
    const int slot = wid >> 1;
    const int half = wid & 1;
    const int ltid = (half << 6) | lane;
    const int a16  = lane & 15;
    const int q    = lane >> 4;

    const int img = blockIdx.x * 4 + slot;         // c*1024 + b*32 + oc
    const int c  = img >> 10;
    const int b  = (img >> 5) & 31;
    const int oc = img & 31;

    for (int t = tid; t < 4096; t += 512) {
        int a = t >> 6, bb = t & 63;
        float sn, cs;
        __sincosf(PI2 * (float)((a*bb) & 63) * (1.f/64.f), &sn, &cs);
        mats[0][a*72 + bb] = f2h(cs);
        mats[1][a*72 + bb] = f2h(sn);
    }

    // stage E^T: ETre[k][hf], ETim[k][hf], stride 72. Rows k=33..47 MUST be zero.
    u16* ETre = wbuf[slot];
    u16* ETim = wbuf[slot] + 48*72;
    for (int j = 33*72 + ltid; j < 48*72; j += 128) {
        ETre[j] = 0;
        ETim[j] = 0;
    }
    const u32* __restrict__ srcP = PT + (size_t)img * NBIN;
    for (int i = 0; i < 17; ++i) {
        int t = i*128 + ltid;
        if (t < NBIN) {
            int hf = t / 33, k = t - hf*33;
            float2 v = upk(srcP[t]);
            ETre[k*72 + hf] = f2h(v.x);
            ETim[k*72 + hf] = f2h(v.y);
        }
    }
    __syncthreads();

    // preload this wave's E^T A-fragments (mt = 2*half + mtl, valid mt < 3)
    f16x8 ere[2][2], eim[2][2];
    #pragma unroll
    for (int mtl = 0; mtl < 2; ++mtl) {
        const int mt = 2*half + mtl;
        if (mt < 3) {
            #pragma unroll
            for (int ks = 0; ks < 2; ++ks) {
                ere[mtl][ks] = *(const f16x8*)&ETre[(16*mt + a16)*72 + ks*32 + q*8];
                eim[mtl][ks] = *(const f16x8*)&ETim[(16*mt + a16)*72 + ks*32 + q*8];
            }
        }
    }
    __syncthreads();

    // step1: T_re^T = Ere*C - Eim*S ; T_im^T = Ere*S + Eim*C; D-layout writes T[h][m]
    u16* Tre = wbuf[slot];             // [64][56]
    u16* Tim = wbuf[slot] + 64*56;
    #pragma unroll
    for (int mtl = 0; mtl < 2; ++mtl) {
        const int mt = 2*half + mtl;
        if (mt < 3) {
            #pragma unroll
            for (int nt = 0; nt < 4; ++nt) {
                f32x4 tre = (f32x4){0,0,0,0}, tim = (f32x4){0,0,0,0};
                #pragma unroll
                for (int ks = 0; ks < 2; ++ks) {
                    const int rb = (16*nt + a16)*72 + ks*32 + q*8;
                    f16x8 cf = *(const f16x8*)&mats[0][rb];
                    f16x8 sf = *(const f16x8*)&mats[1][rb];
                    tre = __builtin_amdgcn_mfma_f32_16x16x32_f16(ere[mtl][ks], cf, tre, 0, 0, 0);
                    tre = __builtin_amdgcn_mfma_f32_16x16x32_f16(eim[mtl][ks], negh(sf), tre, 0, 0, 0);
                    tim = __builtin_amdgcn_mfma_f32_16x16x32_f16(ere[mtl][ks], sf, tim, 0, 0, 0);
                    tim = __builtin_amdgcn_mfma_f32_16x16x32_f16(eim[mtl][ks], cf, tim, 0, 0, 0);
                }
                const int m0 = 16*mt + 4*q;        // row = m, col = h
                u16x4 r4, i4;
                #pragma unroll
                for (int r = 0; r < 4; ++r) {
                    int m = m0 + r;
                    float s = (m == 0 || m == 32) ? (1.f/4096.f) : (2.f/4096.f);
                    r4[r] = (m < 33) ? f2h(tre[r] * s) : (u16)0;
                    i4[r] = (m < 33) ? f2h(tim[r] * s) : (u16)0;
                }
                *(u16x4*)&Tre[(16*nt + a16)*56 + m0] = r4;
                *(u16x4*)&Tim[(16*nt + a16)*56 + m0] = i4;
            }
        }
    }
    __syncthreads();

    // step2: out[h][w] = sum_m Tre[h][m]*C[w][m] - Tim[h][m]*S[w][m]
    float* __restrict__ dst = out + ((size_t)b*128 + (size_t)c*32 + oc) * (FH*FW);
    #pragma unroll
    for (int mtl = 0; mtl < 2; ++mtl) {
        const int mt = 2*half + mtl;
        f16x8 tfr[2], tfi[2];
        #pragma unroll
        for (int ks = 0; ks < 2; ++ks) {
            const int mbase = ks*32 + q*8;
            if (mbase < 48) {
                tfr[ks] = *(const f16x8*)&Tre[(16*mt + a16)*56 + mbase];
                tfi[ks] = *(const f16x8*)&Tim[(16*mt + a16)*56 + mbase];
            } else {
                tfr[ks] = (f16x8){0,0,0,0,0,0,0,0};
                tfi[ks] = (f16x8){0,0,0,0,0,0,0,0};
            }
        }
        #pragma unroll
        for (int nt = 0; nt < 4; ++nt) {
            f32x4 acc = (f32x4){0,0,0,0};
            #pragma unroll
            for (int ks = 0; ks < 2; ++ks) {
                const int rb = (16*nt + a16)*72 + ks*32 + q*8;
                f16x8 cf = *(const f16x8*)&mats[0][rb];
                f16x8 sf = *(const f16x8*)&mats[1][rb];
                acc = __builtin_amdgcn_mfma_f32_16x16x32_f16(tfr[ks], cf, acc, 0, 0, 0);
                acc = __builtin_amdgcn_mfma_f32_16x16x32_f16(tfi[ks], negh(sf), acc, 0, 0, 0);
            }
            // col = w = 16nt+a16, row = h = 16mt+4q+r
            #pragma unroll
            for (int r = 0; r < 4; ++r)
                dst[(16*mt + 4*q + r)*64 + 16*nt + a16] = acc[r];
        }
    }
}

extern "C" void kernel_launch(void* const* d_in, const int* in_sizes, int n_in,
                              void* d_out, int out_size, void* d_ws, size_t ws_size,
                              hipStream_t stream)
{
    const float* x   = (const float*)d_in[0];
    const float* krw = (const float*)d_in[1];
    const float* krx = (const float*)d_in[2];
    const float* kry = (const float*)d_in[3];
    const float* krz = (const float*)d_in[4];
    const float* kiw = (const float*)d_in[5];
    const float* kix = (const float*)d_in[6];
    const float* kiy = (const float*)d_in[7];
    const float* kiz = (const float*)d_in[8];

    // ws regions (34.6 MB each): [XT / PT] [WT] [Xs / P]
    const size_t R = (size_t)NBIN * 8192 * sizeof(u16);   // 34.6 MB
    u16* XT = (u16*)d_ws;
    u32* PT = (u32*)d_ws;                                  // alias: XT dead after contract
    u16* WT = (u16*)((char*)d_ws + R);
    u32* Xs = (u32*)((char*)d_ws + 2*R);
    u32* P  = Xs;                                          // alias: Xs dead after xpose
    float* out = (float*)d_out;

    fwd_prep_kernel<<<dim3(1024 + 2112), 256, 0, stream>>>(x, Xs,
                                                           krw, krx, kry, krz,
                                                           kiw, kix, kiy, kiz, WT);
    xpose_x_kernel<<<dim3(128, NBIN/32), 256, 0, stream>>>(Xs, (u32*)XT);
    contract_kernel<<<dim3(NBIN), 256, 0, stream>>>(XT, WT, P);
    pxpose_kernel<<<dim3(NBIN/32, NIMG/32), 256, 0, stream>>>(P, PT);
    fft_inv_kernel<<<dim3(NIMG/4), 512, 0, stream>>>(PT, out);
}

// Round 15
// 102.752 us; speedup vs baseline: 2.0711x; 1.1443x over previous
//
#include <hip/hip_runtime.h>

#define FH 64
#define FW 64
#define NWF 33
#define NBIN (FH*NWF)      // 2112
#define NIMG 4096          // 4 * 32 * 32
#define PI2 6.283185307179586f

typedef unsigned short u16;
typedef unsigned int u32;
typedef __attribute__((ext_vector_type(8))) short bf16x8;
typedef __attribute__((ext_vector_type(8))) _Float16 f16x8;
typedef __attribute__((ext_vector_type(4))) unsigned short u16x4;
typedef __attribute__((ext_vector_type(4))) float f32x4;
typedef __attribute__((ext_vector_type(4))) int   i32x4;

__device__ __forceinline__ u16 f2bf(float f) {
    unsigned u = __float_as_uint(f);
    unsigned r = (u + 0x7FFFu + ((u >> 16) & 1u)) >> 16;   // RNE
    return (u16)r;
}
__device__ __forceinline__ u16 f2h(float f) {
    _Float16 h = (_Float16)f;
    return __builtin_bit_cast(u16, h);
}
__device__ __forceinline__ float2 upk(u32 v) {
    return make_float2(__uint_as_float(v << 16), __uint_as_float(v & 0xFFFF0000u));
}
__device__ __forceinline__ u32 pk(float2 v) {
    return (u32)f2bf(v.x) | ((u32)f2bf(v.y) << 16);
}
__device__ __forceinline__ f16x8 negh(f16x8 v) {
    i32x4 t = __builtin_bit_cast(i32x4, v);
    t ^= (int)0x80008000;
    return __builtin_bit_cast(f16x8, t);
}

// ================= FAT KERNEL (round-11 proven): fft_fwd (blocks 0..1023) ∥ prep_w ==========
__global__ __launch_bounds__(512, 4) void fwd_prep_kernel(
    const float* __restrict__ x, u32* __restrict__ Xs,
    const float* __restrict__ s0, const float* __restrict__ s1,
    const float* __restrict__ s2, const float* __restrict__ s3,
    const float* __restrict__ s4, const float* __restrict__ s5,
    const float* __restrict__ s6, const float* __restrict__ s7,
    u16* __restrict__ WT)
{
    __shared__ __align__(16) u16 sm[36864];
    const int tid = threadIdx.x;

    if (blockIdx.x < 1024) {
        const int lane = tid & 63;
        const int wid  = tid >> 6;         // 0..7
        const int slot = wid >> 1;         // image slot 0..3
        const int half = wid & 1;          // M-split half
        const int a16  = lane & 15;
        const int q    = lane >> 4;

        const int img = blockIdx.x * 4 + slot;     // qc*1024 + b*32 + ci
        const int qc = img >> 10;
        const int b  = (img >> 5) & 31;
        const int ci = img & 31;
        const float* __restrict__ src = x + ((size_t)b*128 + (size_t)qc*32 + ci) * (FH*FW);

        u16* mats0 = sm;                   // cos[a*72+b]
        u16* mats1 = sm + 64*72;           // sin[a*72+b]
        u16* ST    = sm + 9216 + slot*6912;

        for (int t = tid; t < 4096; t += 512) {
            int a = t >> 6, bb = t & 63;
            float sn, cs;
            __sincosf(PI2 * (float)((a*bb) & 63) * (1.f/64.f), &sn, &cs);
            mats0[a*72 + bb] = f2h(cs);
            mats1[a*72 + bb] = f2h(sn);
        }

        // A-fragments straight from global
        f16x8 xf[2][2];
        #pragma unroll
        for (int mtl = 0; mtl < 2; ++mtl)
            #pragma unroll
            for (int ks = 0; ks < 2; ++ks) {
                const float* rp = src + (16*(2*half + mtl) + a16)*64 + ks*32 + q*8;
                float4 v0 = *(const float4*)rp;
                float4 v1 = *(const float4*)(rp + 4);
                xf[mtl][ks] = (f16x8){ (_Float16)v0.x, (_Float16)v0.y, (_Float16)v0.z, (_Float16)v0.w,
                                       (_Float16)v1.x, (_Float16)v1.y, (_Float16)v1.z, (_Float16)v1.w };
            }
        __syncthreads();   // mats ready

        // step1: S_re = x*C, S_im = -x*S; store transposed S_T[ri][k][h], stride 72
        #pragma unroll
        for (int mtl = 0; mtl < 2; ++mtl) {
            const int mt = 2*half + mtl;
            f32x4 are[3], aim[3];
            #pragma unroll
            for (int nt = 0; nt < 3; ++nt) { are[nt] = (f32x4){0,0,0,0}; aim[nt] = (f32x4){0,0,0,0}; }
            #pragma unroll
            for (int nt = 0; nt < 3; ++nt)
                #pragma unroll
                for (int ks = 0; ks < 2; ++ks) {
                    const int rb = (16*nt + a16)*72 + ks*32 + q*8;
                    f16x8 cf = *(const f16x8*)&mats0[rb];
                    f16x8 sf = *(const f16x8*)&mats1[rb];
                    are[nt] = __builtin_amdgcn_mfma_f32_16x16x32_f16(xf[mtl][ks], cf, are[nt], 0, 0, 0);
                    aim[nt] = __builtin_amdgcn_mfma_f32_16x16x32_f16(xf[mtl][ks], negh(sf), aim[nt], 0, 0, 0);
                }
            const int hb = 16*mt + 4*q;
            #pragma unroll
            for (int nt = 0; nt < 3; ++nt) {
                u16x4 re4 = { f2h(are[nt][0]), f2h(are[nt][1]), f2h(are[nt][2]), f2h(are[nt][3]) };
                u16x4 im4 = { f2h(aim[nt][0]), f2h(aim[nt][1]), f2h(aim[nt][2]), f2h(aim[nt][3]) };
                *(u16x4*)&ST[(16*nt + a16)*72 + hb]      = re4;
                *(u16x4*)&ST[(48 + 16*nt + a16)*72 + hb] = im4;
            }
        }
        __syncthreads();   // ST complete

        f16x8 bfr[2][3][2];
        #pragma unroll
        for (int ri = 0; ri < 2; ++ri)
            #pragma unroll
            for (int nt = 0; nt < 3; ++nt)
                #pragma unroll
                for (int ks = 0; ks < 2; ++ks)
                    bfr[ri][nt][ks] = *(const f16x8*)&ST[(ri*48 + 16*nt + a16)*72 + ks*32 + q*8];

        // step2: X_re = C*S_re + S*S_im ; X_im = C*S_im - S*S_re; direct global store
        u32* __restrict__ dst = Xs + (size_t)img * NBIN;
        #pragma unroll
        for (int mtl = 0; mtl < 2; ++mtl) {
            const int mt = 2*half + mtl;
            f16x8 cfa[2], sfa[2], nsf[2];
            #pragma unroll
            for (int ks = 0; ks < 2; ++ks) {
                const int rb = (16*mt + a16)*72 + ks*32 + q*8;
                cfa[ks] = *(const f16x8*)&mats0[rb];
                sfa[ks] = *(const f16x8*)&mats1[rb];
                nsf[ks] = negh(sfa[ks]);
            }
            #pragma unroll
            for (int nt = 0; nt < 3; ++nt) {
                f32x4 xre = (f32x4){0,0,0,0}, xim = (f32x4){0,0,0,0};
                #pragma unroll
                for (int ks = 0; ks < 2; ++ks) {
                    xre = __builtin_amdgcn_mfma_f32_16x16x32_f16(cfa[ks], bfr[0][nt][ks], xre, 0, 0, 0);
                    xre = __builtin_amdgcn_mfma_f32_16x16x32_f16(sfa[ks], bfr[1][nt][ks], xre, 0, 0, 0);
                    xim = __builtin_amdgcn_mfma_f32_16x16x32_f16(cfa[ks], bfr[1][nt][ks], xim, 0, 0, 0);
                    xim = __builtin_amdgcn_mfma_f32_16x16x32_f16(nsf[ks], bfr[0][nt][ks], xim, 0, 0, 0);
                }
                const int k = 16*nt + a16;     // col of D; row hf = 16mt+4q+r
                if (k < 33) {
                    #pragma unroll
                    for (int r = 0; r < 4; ++r)
                        dst[(16*mt + 4*q + r)*33 + k] = pk(make_float2(xre[r], xim[r]));
                }
            }
        }
    } else {
        // ---------------- transpose W (tiled): [i][o][bin] f32 -> [bin][p][ri][o][i] bf16 --------
        const int pb = blockIdx.x - 1024;   // 0..2111
        const int bt = pb % 66;             // bin tile
        const int ay = pb / 66;             // 0..31
        const int a  = ay >> 2;             // array 0..7
        const int o0 = (ay & 3) * 8;
        const float* __restrict__ src =
            (a==0)?s0:(a==1)?s1:(a==2)?s2:(a==3)?s3:(a==4)?s4:(a==5)?s5:(a==6)?s6:s7;
        const int bin0 = bt * 32;
        u16* lds2 = sm;                     // [binL][chL], stride 264

        #pragma unroll
        for (int it = 0; it < 4; ++it) {
            int e = tid + it*512;           // 2048 float4 tasks
            int f4 = e & 7, rt = e >> 3;
            int i = rt & 31, oo = rt >> 5;
            int io = i*32 + o0 + oo;
            float4 v = ((const float4*)src)[(size_t)io*(NBIN/4) + bt*8 + f4];
            int chL = oo*32 + i;
            int bb = f4*4;
            lds2[(bb+0)*264 + chL] = f2bf(v.x);
            lds2[(bb+1)*264 + chL] = f2bf(v.y);
            lds2[(bb+2)*264 + chL] = f2bf(v.z);
            lds2[(bb+3)*264 + chL] = f2bf(v.w);
        }
        __syncthreads();
        const int p = a & 3, ri = a >> 2;
        #pragma unroll
        for (int it = 0; it < 2; ++it) {
            int e = tid + it*512;           // 1024 bf16x8 tasks
            int binL = e >> 5, c8 = e & 31;
            bf16x8 v = *(const bf16x8*)&lds2[binL*264 + c8*8];
            size_t d = ((size_t)(bin0 + binL)*8 + p*2 + ri)*1024 + o0*32 + c8*8;
            *(bf16x8*)(WT + d) = v;
        }
    }
}

// ---------------- transpose X: [img][bin] u32 -> [bin][q][ri][b][i] bf16 ----------------
__global__ __launch_bounds__(256) void xpose_x_kernel(const u32* __restrict__ Xs,
                                                      u32* __restrict__ XT)
{
    const int g    = blockIdx.x;        // q*32 + b
    const int bin0 = blockIdx.y * 32;
    __shared__ u32 tile[32][33];
    const int tid = threadIdx.x;
    #pragma unroll
    for (int it = 0; it < 4; ++it) {
        int e = tid + it*256;
        int imgL = e >> 5, binL = e & 31;
        tile[imgL][binL] = Xs[(size_t)(g*32 + imgL) * NBIN + bin0 + binL];
    }
    __syncthreads();
    const int q = g >> 5, b = g & 31;
    #pragma unroll
    for (int it = 0; it < 2; ++it) {
        int e = tid + it*256;          // 512 tasks: [binL][i-pair]
        int binL = e >> 4, pr = e & 15;
        u32 v0 = tile[pr*2][binL], v1 = tile[pr*2 + 1][binL];
        u32 re = (v0 & 0xFFFFu) | (v1 << 16);
        u32 im = (v0 >> 16) | (v1 & 0xFFFF0000u);
        size_t base = ((size_t)(bin0 + binL)*8 + q*2) * 512 + b*16 + pr;  // u32 units
        XT[base]       = re;
        XT[base + 512] = im;
    }
}

// ---------------- per-bin quaternion contraction via MFMA ----------------
__global__ __launch_bounds__(256) void contract_kernel(
    const u16* __restrict__ XT, const u16* __restrict__ WT,
    u32* __restrict__ P)
{
    const int bid  = blockIdx.x;
    const int bin  = (bid & 7) * (NBIN/8) + (bid >> 3);   // chunked XCD swizzle
    const int wid  = threadIdx.x >> 6;
    const int lane = threadIdx.x & 63;
    const int bh = wid >> 1, oh = wid & 1;
    const int row = lane & 15, kg = lane >> 4;

    const u16* __restrict__ xb = XT + (size_t)bin * 8192;
    const u16* __restrict__ wb = WT + (size_t)bin * 8192;

    bf16x8 ax[4][2];
    #pragma unroll
    for (int q = 0; q < 4; ++q)
        #pragma unroll
        for (int ri = 0; ri < 2; ++ri)
            ax[q][ri] = *(const bf16x8*)(xb + ((q*2 + ri)*32 + bh*16 + row)*32 + kg*8);

    bf16x8 wpos[4][2], wneg[4][2];
    #pragma unroll
    for (int p = 0; p < 4; ++p)
        #pragma unroll
        for (int ri = 0; ri < 2; ++ri) {
            bf16x8 w = *(const bf16x8*)(wb + ((p*2 + ri)*32 + oh*16 + row)*32 + kg*8);
            wpos[p][ri] = w;
            i32x4 t = __builtin_bit_cast(i32x4, w);
            t ^= (int)0x80008000;
            wneg[p][ri] = __builtin_bit_cast(bf16x8, t);
        }

    f32x4 acc[4][2];
    #pragma unroll
    for (int c = 0; c < 4; ++c)
        #pragma unroll
        for (int ri = 0; ri < 2; ++ri)
            acc[c][ri] = (f32x4){0.f, 0.f, 0.f, 0.f};

    constexpr int PI_[4][4] = {{0,1,2,3},{1,0,3,2},{2,3,0,1},{3,2,1,0}};
    constexpr int SG_[4][4] = {{1,-1,-1,-1},{1,1,-1,1},{1,1,1,-1},{1,-1,1,1}};
    #pragma unroll
    for (int c = 0; c < 4; ++c)
        #pragma unroll
        for (int q = 0; q < 4; ++q) {
            const int  p   = PI_[c][q];
            const bool pos = SG_[c][q] > 0;
            bf16x8 wr_s = pos ? wpos[p][0] : wneg[p][0];
            bf16x8 wi_s = pos ? wpos[p][1] : wneg[p][1];
            bf16x8 wi_m = pos ? wneg[p][1] : wpos[p][1];
            acc[c][0] = __builtin_amdgcn_mfma_f32_16x16x32_bf16(ax[q][0], wr_s, acc[c][0], 0, 0, 0);
            acc[c][0] = __builtin_amdgcn_mfma_f32_16x16x32_bf16(ax[q][1], wi_m, acc[c][0], 0, 0, 0);
            acc[c][1] = __builtin_amdgcn_mfma_f32_16x16x32_bf16(ax[q][1], wr_s, acc[c][1], 0, 0, 0);
            acc[c][1] = __builtin_amdgcn_mfma_f32_16x16x32_bf16(ax[q][0], wi_s, acc[c][1], 0, 0, 0);
        }

    u32* __restrict__ dst = P + (size_t)bin * 4096;
    #pragma unroll
    for (int c = 0; c < 4; ++c)
        #pragma unroll
        for (int r = 0; r < 4; ++r) {
            int b_ = bh*16 + kg*4 + r;
            int o  = oh*16 + row;
            dst[c*1024 + b_*32 + o] = pk(make_float2(acc[c][0][r], acc[c][1][r]));
        }
}

// ---------------- inverse rfft2 via MFMA-DFT: reads P[bin][img] DIRECTLY (pxpose gone) ------
// Block of 4 consecutive imgs -> per bin a 16 B contiguous gather; bijective chunked XCD
// swizzle co-locates the 4 blocks sharing each 64 B line so L2 serves the reuse.
__global__ __launch_bounds__(512, 4) void fft_inv_kernel(const u32* __restrict__ P,
                                                         float* __restrict__ out)
{
    __shared__ __align__(16) u16 mats[2][64*72];   // cos/sin(+2pi ab/64), symmetric
    __shared__ __align__(16) u16 wbuf[4][7168];    // per-image: ET (2x48x72) / T (2x64x56)

    const int tid  = threadIdx.x;
    const int lane = tid & 63;
    const int wid  = tid >> 6;
    const int slot = wid >> 1;
    const int half = wid & 1;
    const int ltid = (half << 6) | lane;
    const int a16  = lane & 15;
    const int q    = lane >> 4;

    const int bid = blockIdx.x;
    const int g   = (bid & 7) * 128 + (bid >> 3);  // bijective: 1024 = 8 x 128
    const int img = g * 4 + slot;                  // c*1024 + b*32 + oc
    const int c  = img >> 10;
    const int b  = (img >> 5) & 31;
    const int oc = img & 31;

    for (int t = tid; t < 4096; t += 512) {
        int a = t >> 6, bb = t & 63;
        float sn, cs;
        __sincosf(PI2 * (float)((a*bb) & 63) * (1.f/64.f), &sn, &cs);
        mats[0][a*72 + bb] = f2h(cs);
        mats[1][a*72 + bb] = f2h(sn);
    }

    // zero the garbage rows k=33..47 of this slot's ET (MFMA A-rows must be 0, not stale)
    {
        u16* ETre = wbuf[slot];
        u16* ETim = wbuf[slot] + 48*72;
        for (int j = 33*72 + ltid; j < 48*72; j += 128) {
            ETre[j] = 0;
            ETim[j] = 0;
        }
    }
    // block-wide gather: for each bin, 4 consecutive u32 (the block's 4 images)
    for (int e = tid; e < NBIN*4; e += 512) {
        int bin = e >> 2, sl = e & 3;
        u32 v = P[(size_t)bin * 4096 + g*4 + sl];
        float2 f = upk(v);
        int hf = bin / 33, k = bin - hf*33;
        u16* ETre = wbuf[sl];
        u16* ETim = wbuf[sl] + 48*72;
        ETre[k*72 + hf] = f2h(f.x);
        ETim[k*72 + hf] = f2h(f.y);
    }
    __syncthreads();

    // preload this wave's E^T A-fragments (mt = 2*half + mtl, valid mt < 3)
    u16* ETre = wbuf[slot];
    u16* ETim = wbuf[slot] + 48*72;
    f16x8 ere[2][2], eim[2][2];
    #pragma unroll
    for (int mtl = 0; mtl < 2; ++mtl) {
        const int mt = 2*half + mtl;
        if (mt < 3) {
            #pragma unroll
            for (int ks = 0; ks < 2; ++ks) {
                ere[mtl][ks] = *(const f16x8*)&ETre[(16*mt + a16)*72 + ks*32 + q*8];
                eim[mtl][ks] = *(const f16x8*)&ETim[(16*mt + a16)*72 + ks*32 + q*8];
            }
        }
    }
    __syncthreads();

    // step1: T_re^T = Ere*C - Eim*S ; T_im^T = Ere*S + Eim*C; D-layout writes T[h][m]
    u16* Tre = wbuf[slot];             // [64][56]
    u16* Tim = wbuf[slot] + 64*56;
    #pragma unroll
    for (int mtl = 0; mtl < 2; ++mtl) {
        const int mt = 2*half + mtl;
        if (mt < 3) {
            #pragma unroll
            for (int nt = 0; nt < 4; ++nt) {
                f32x4 tre = (f32x4){0,0,0,0}, tim = (f32x4){0,0,0,0};
                #pragma unroll
                for (int ks = 0; ks < 2; ++ks) {
                    const int rb = (16*nt + a16)*72 + ks*32 + q*8;
                    f16x8 cf = *(const f16x8*)&mats[0][rb];
                    f16x8 sf = *(const f16x8*)&mats[1][rb];
                    tre = __builtin_amdgcn_mfma_f32_16x16x32_f16(ere[mtl][ks], cf, tre, 0, 0, 0);
                    tre = __builtin_amdgcn_mfma_f32_16x16x32_f16(eim[mtl][ks], negh(sf), tre, 0, 0, 0);
                    tim = __builtin_amdgcn_mfma_f32_16x16x32_f16(ere[mtl][ks], sf, tim, 0, 0, 0);
                    tim = __builtin_amdgcn_mfma_f32_16x16x32_f16(eim[mtl][ks], cf, tim, 0, 0, 0);
                }
                const int m0 = 16*mt + 4*q;        // row = m, col = h
                u16x4 r4, i4;
                #pragma unroll
                for (int r = 0; r < 4; ++r) {
                    int m = m0 + r;
                    float s = (m == 0 || m == 32) ? (1.f/4096.f) : (2.f/4096.f);
                    r4[r] = (m < 33) ? f2h(tre[r] * s) : (u16)0;
                    i4[r] = (m < 33) ? f2h(tim[r] * s) : (u16)0;
                }
                *(u16x4*)&Tre[(16*nt + a16)*56 + m0] = r4;
                *(u16x4*)&Tim[(16*nt + a16)*56 + m0] = i4;
            }
        }
    }
    __syncthreads();

    // step2: out[h][w] = sum_m Tre[h][m]*C[w][m] - Tim[h][m]*S[w][m]
    float* __restrict__ dst = out + ((size_t)b*128 + (size_t)c*32 + oc) * (FH*FW);
    #pragma unroll
    for (int mtl = 0; mtl < 2; ++mtl) {
        const int mt = 2*half + mtl;
        f16x8 tfr[2], tfi[2];
        #pragma unroll
        for (int ks = 0; ks < 2; ++ks) {
            const int mbase = ks*32 + q*8;
            if (mbase < 48) {
                tfr[ks] = *(const f16x8*)&Tre[(16*mt + a16)*56 + mbase];
                tfi[ks] = *(const f16x8*)&Tim[(16*mt + a16)*56 + mbase];
            } else {
                tfr[ks] = (f16x8){0,0,0,0,0,0,0,0};
                tfi[ks] = (f16x8){0,0,0,0,0,0,0,0};
            }
        }
        #pragma unroll
        for (int nt = 0; nt < 4; ++nt) {
            f32x4 acc = (f32x4){0,0,0,0};
            #pragma unroll
            for (int ks = 0; ks < 2; ++ks) {
                const int rb = (16*nt + a16)*72 + ks*32 + q*8;
                f16x8 cf = *(const f16x8*)&mats[0][rb];
                f16x8 sf = *(const f16x8*)&mats[1][rb];
                acc = __builtin_amdgcn_mfma_f32_16x16x32_f16(tfr[ks], cf, acc, 0, 0, 0);
                acc = __builtin_amdgcn_mfma_f32_16x16x32_f16(tfi[ks], negh(sf), acc, 0, 0, 0);
            }
            // col = w = 16nt+a16, row = h = 16mt+4q+r
            #pragma unroll
            for (int r = 0; r < 4; ++r)
                dst[(16*mt + 4*q + r)*64 + 16*nt + a16] = acc[r];
        }
    }
}

extern "C" void kernel_launch(void* const* d_in, const int* in_sizes, int n_in,
                              void* d_out, int out_size, void* d_ws, size_t ws_size,
                              hipStream_t stream)
{
    const float* x   = (const float*)d_in[0];
    const float* krw = (const float*)d_in[1];
    const float* krx = (const float*)d_in[2];
    const float* kry = (const float*)d_in[3];
    const float* krz = (const float*)d_in[4];
    const float* kiw = (const float*)d_in[5];
    const float* kix = (const float*)d_in[6];
    const float* kiy = (const float*)d_in[7];
    const float* kiz = (const float*)d_in[8];

    // ws regions (34.6 MB each): [XT] [WT] [Xs / P aliased]
    const size_t R = (size_t)NBIN * 8192 * sizeof(u16);   // 34.6 MB
    u16* XT = (u16*)d_ws;
    u16* WT = (u16*)((char*)d_ws + R);
    u32* Xs = (u32*)((char*)d_ws + 2*R);
    u32* P  = Xs;                                          // alias: Xs dead after xpose
    float* out = (float*)d_out;

    fwd_prep_kernel<<<dim3(1024 + 2112), 512, 0, stream>>>(x, Xs,
                                                           krw, krx, kry, krz,
                                                           kiw, kix, kiy, kiz, WT);
    xpose_x_kernel<<<dim3(128, NBIN/32), 256, 0, stream>>>(Xs, (u32*)XT);
    contract_kernel<<<dim3(NBIN), 256, 0, stream>>>(XT, WT, P);
    fft_inv_kernel<<<dim3(NIMG/4), 512, 0, stream>>>(P, out);
}

// Round 16
// 100.764 us; speedup vs baseline: 2.1120x; 1.0197x over previous
//
#include <hip/hip_runtime.h>

#define FH 64
#define FW 64
#define NWF 33
#define NBIN (FH*NWF)      // 2112
#define NIMG 4096          // 4 * 32 * 32
#define PI2 6.283185307179586f

typedef unsigned short u16;
typedef unsigned int u32;
typedef __attribute__((ext_vector_type(8))) short bf16x8;
typedef __attribute__((ext_vector_type(8))) _Float16 f16x8;
typedef __attribute__((ext_vector_type(4))) unsigned short u16x4;
typedef __attribute__((ext_vector_type(4))) float f32x4;
typedef __attribute__((ext_vector_type(4))) int   i32x4;

__device__ __forceinline__ u16 f2bf(float f) {
    unsigned u = __float_as_uint(f);
    unsigned r = (u + 0x7FFFu + ((u >> 16) & 1u)) >> 16;   // RNE
    return (u16)r;
}
__device__ __forceinline__ u16 f2h(float f) {
    _Float16 h = (_Float16)f;
    return __builtin_bit_cast(u16, h);
}
__device__ __forceinline__ float2 upk(u32 v) {
    return make_float2(__uint_as_float(v << 16), __uint_as_float(v & 0xFFFF0000u));
}
__device__ __forceinline__ u32 pk(float2 v) {
    return (u32)f2bf(v.x) | ((u32)f2bf(v.y) << 16);
}
__device__ __forceinline__ f16x8 negh(f16x8 v) {
    i32x4 t = __builtin_bit_cast(i32x4, v);
    t ^= (int)0x80008000;
    return __builtin_bit_cast(f16x8, t);
}

// ======= FAT KERNEL, INTERLEAVED IDs: 3136 = 49*64; per 49 bids -> 16 fwd + 33 prep =======
// Interleaving breaks the phase convoy: resident set is always a fwd/prep mix, so prep's
// streaming fills fwd's compute phases and vice versa (r11/r15 ran them temporally split).
__global__ __launch_bounds__(512, 4) void fwd_prep_kernel(
    const float* __restrict__ x, u32* __restrict__ Xs,
    const float* __restrict__ s0, const float* __restrict__ s1,
    const float* __restrict__ s2, const float* __restrict__ s3,
    const float* __restrict__ s4, const float* __restrict__ s5,
    const float* __restrict__ s6, const float* __restrict__ s7,
    u16* __restrict__ WT)
{
    __shared__ __align__(16) u16 sm[36864];
    const int tid = threadIdx.x;
    const int grp = blockIdx.x / 49;
    const int rem = blockIdx.x - grp*49;

    if (rem < 16) {
        const int fb = grp*16 + rem;       // 0..1023
        const int lane = tid & 63;
        const int wid  = tid >> 6;         // 0..7
        const int slot = wid >> 1;         // image slot 0..3
        const int half = wid & 1;          // M-split half
        const int a16  = lane & 15;
        const int q    = lane >> 4;

        const int img = fb * 4 + slot;     // qc*1024 + b*32 + ci
        const int qc = img >> 10;
        const int b  = (img >> 5) & 31;
        const int ci = img & 31;
        const float* __restrict__ src = x + ((size_t)b*128 + (size_t)qc*32 + ci) * (FH*FW);

        u16* mats0 = sm;                   // cos[a*72+b]
        u16* mats1 = sm + 64*72;           // sin[a*72+b]
        u16* ST    = sm + 9216 + slot*6912;

        for (int t = tid; t < 4096; t += 512) {
            int a = t >> 6, bb = t & 63;
            float sn, cs;
            __sincosf(PI2 * (float)((a*bb) & 63) * (1.f/64.f), &sn, &cs);
            mats0[a*72 + bb] = f2h(cs);
            mats1[a*72 + bb] = f2h(sn);
        }

        // A-fragments straight from global
        f16x8 xf[2][2];
        #pragma unroll
        for (int mtl = 0; mtl < 2; ++mtl)
            #pragma unroll
            for (int ks = 0; ks < 2; ++ks) {
                const float* rp = src + (16*(2*half + mtl) + a16)*64 + ks*32 + q*8;
                float4 v0 = *(const float4*)rp;
                float4 v1 = *(const float4*)(rp + 4);
                xf[mtl][ks] = (f16x8){ (_Float16)v0.x, (_Float16)v0.y, (_Float16)v0.z, (_Float16)v0.w,
                                       (_Float16)v1.x, (_Float16)v1.y, (_Float16)v1.z, (_Float16)v1.w };
            }
        __syncthreads();   // mats ready

        // step1: S_re = x*C, S_im = -x*S; store transposed S_T[ri][k][h], stride 72
        #pragma unroll
        for (int mtl = 0; mtl < 2; ++mtl) {
            const int mt = 2*half + mtl;
            f32x4 are[3], aim[3];
            #pragma unroll
            for (int nt = 0; nt < 3; ++nt) { are[nt] = (f32x4){0,0,0,0}; aim[nt] = (f32x4){0,0,0,0}; }
            #pragma unroll
            for (int nt = 0; nt < 3; ++nt)
                #pragma unroll
                for (int ks = 0; ks < 2; ++ks) {
                    const int rb = (16*nt + a16)*72 + ks*32 + q*8;
                    f16x8 cf = *(const f16x8*)&mats0[rb];
                    f16x8 sf = *(const f16x8*)&mats1[rb];
                    are[nt] = __builtin_amdgcn_mfma_f32_16x16x32_f16(xf[mtl][ks], cf, are[nt], 0, 0, 0);
                    aim[nt] = __builtin_amdgcn_mfma_f32_16x16x32_f16(xf[mtl][ks], negh(sf), aim[nt], 0, 0, 0);
                }
            const int hb = 16*mt + 4*q;
            #pragma unroll
            for (int nt = 0; nt < 3; ++nt) {
                u16x4 re4 = { f2h(are[nt][0]), f2h(are[nt][1]), f2h(are[nt][2]), f2h(are[nt][3]) };
                u16x4 im4 = { f2h(aim[nt][0]), f2h(aim[nt][1]), f2h(aim[nt][2]), f2h(aim[nt][3]) };
                *(u16x4*)&ST[(16*nt + a16)*72 + hb]      = re4;
                *(u16x4*)&ST[(48 + 16*nt + a16)*72 + hb] = im4;
            }
        }
        __syncthreads();   // ST complete

        f16x8 bfr[2][3][2];
        #pragma unroll
        for (int ri = 0; ri < 2; ++ri)
            #pragma unroll
            for (int nt = 0; nt < 3; ++nt)
                #pragma unroll
                for (int ks = 0; ks < 2; ++ks)
                    bfr[ri][nt][ks] = *(const f16x8*)&ST[(ri*48 + 16*nt + a16)*72 + ks*32 + q*8];

        // step2: X_re = C*S_re + S*S_im ; X_im = C*S_im - S*S_re; direct global store
        u32* __restrict__ dst = Xs + (size_t)img * NBIN;
        #pragma unroll
        for (int mtl = 0; mtl < 2; ++mtl) {
            const int mt = 2*half + mtl;
            f16x8 cfa[2], sfa[2], nsf[2];
            #pragma unroll
            for (int ks = 0; ks < 2; ++ks) {
                const int rb = (16*mt + a16)*72 + ks*32 + q*8;
                cfa[ks] = *(const f16x8*)&mats0[rb];
                sfa[ks] = *(const f16x8*)&mats1[rb];
                nsf[ks] = negh(sfa[ks]);
            }
            #pragma unroll
            for (int nt = 0; nt < 3; ++nt) {
                f32x4 xre = (f32x4){0,0,0,0}, xim = (f32x4){0,0,0,0};
                #pragma unroll
                for (int ks = 0; ks < 2; ++ks) {
                    xre = __builtin_amdgcn_mfma_f32_16x16x32_f16(cfa[ks], bfr[0][nt][ks], xre, 0, 0, 0);
                    xre = __builtin_amdgcn_mfma_f32_16x16x32_f16(sfa[ks], bfr[1][nt][ks], xre, 0, 0, 0);
                    xim = __builtin_amdgcn_mfma_f32_16x16x32_f16(cfa[ks], bfr[1][nt][ks], xim, 0, 0, 0);
                    xim = __builtin_amdgcn_mfma_f32_16x16x32_f16(nsf[ks], bfr[0][nt][ks], xim, 0, 0, 0);
                }
                const int k = 16*nt + a16;     // col of D; row hf = 16mt+4q+r
                if (k < 33) {
                    #pragma unroll
                    for (int r = 0; r < 4; ++r)
                        dst[(16*mt + 4*q + r)*33 + k] = pk(make_float2(xre[r], xim[r]));
                }
            }
        }
    } else {
        // ---------------- transpose W (tiled): [i][o][bin] f32 -> [bin][p][ri][o][i] bf16 --------
        const int pb = grp*33 + (rem - 16);  // 0..2111
        const int bt = pb % 66;              // bin tile
        const int ay = pb / 66;              // 0..31
        const int a  = ay >> 2;              // array 0..7
        const int o0 = (ay & 3) * 8;
        const float* __restrict__ src =
            (a==0)?s0:(a==1)?s1:(a==2)?s2:(a==3)?s3:(a==4)?s4:(a==5)?s5:(a==6)?s6:s7;
        const int bin0 = bt * 32;
        u16* lds2 = sm;                     // [binL][chL], stride 264

        #pragma unroll
        for (int it = 0; it < 4; ++it) {
            int e = tid + it*512;           // 2048 float4 tasks
            int f4 = e & 7, rt = e >> 3;
            int i = rt & 31, oo = rt >> 5;
            int io = i*32 + o0 + oo;
            float4 v = ((const float4*)src)[(size_t)io*(NBIN/4) + bt*8 + f4];
            int chL = oo*32 + i;
            int bb = f4*4;
            lds2[(bb+0)*264 + chL] = f2bf(v.x);
            lds2[(bb+1)*264 + chL] = f2bf(v.y);
            lds2[(bb+2)*264 + chL] = f2bf(v.z);
            lds2[(bb+3)*264 + chL] = f2bf(v.w);
        }
        __syncthreads();
        const int p = a & 3, ri = a >> 2;
        #pragma unroll
        for (int it = 0; it < 2; ++it) {
            int e = tid + it*512;           // 1024 bf16x8 tasks
            int binL = e >> 5, c8 = e & 31;
            bf16x8 v = *(const bf16x8*)&lds2[binL*264 + c8*8];
            size_t d = ((size_t)(bin0 + binL)*8 + p*2 + ri)*1024 + o0*32 + c8*8;
            *(bf16x8*)(WT + d) = v;
        }
    }
}

// ---------------- transpose X: [img][bin] u32 -> [bin][q][ri][b][i] bf16 ----------------
__global__ __launch_bounds__(256) void xpose_x_kernel(const u32* __restrict__ Xs,
                                                      u32* __restrict__ XT)
{
    const int g    = blockIdx.x;        // q*32 + b
    const int bin0 = blockIdx.y * 32;
    __shared__ u32 tile[32][33];
    const int tid = threadIdx.x;
    #pragma unroll
    for (int it = 0; it < 4; ++it) {
        int e = tid + it*256;
        int imgL = e >> 5, binL = e & 31;
        tile[imgL][binL] = Xs[(size_t)(g*32 + imgL) * NBIN + bin0 + binL];
    }
    __syncthreads();
    const int q = g >> 5, b = g & 31;
    #pragma unroll
    for (int it = 0; it < 2; ++it) {
        int e = tid + it*256;          // 512 tasks: [binL][i-pair]
        int binL = e >> 4, pr = e & 15;
        u32 v0 = tile[pr*2][binL], v1 = tile[pr*2 + 1][binL];
        u32 re = (v0 & 0xFFFFu) | (v1 << 16);
        u32 im = (v0 >> 16) | (v1 & 0xFFFF0000u);
        size_t base = ((size_t)(bin0 + binL)*8 + q*2) * 512 + b*16 + pr;  // u32 units
        XT[base]       = re;
        XT[base + 512] = im;
    }
}

// ---------------- per-bin quaternion contraction via MFMA ----------------
__global__ __launch_bounds__(256) void contract_kernel(
    const u16* __restrict__ XT, const u16* __restrict__ WT,
    u32* __restrict__ P)
{
    const int bid  = blockIdx.x;
    const int bin  = (bid & 7) * (NBIN/8) + (bid >> 3);   // chunked XCD swizzle
    const int wid  = threadIdx.x >> 6;
    const int lane = threadIdx.x & 63;
    const int bh = wid >> 1, oh = wid & 1;
    const int row = lane & 15, kg = lane >> 4;

    const u16* __restrict__ xb = XT + (size_t)bin * 8192;
    const u16* __restrict__ wb = WT + (size_t)bin * 8192;

    bf16x8 ax[4][2];
    #pragma unroll
    for (int q = 0; q < 4; ++q)
        #pragma unroll
        for (int ri = 0; ri < 2; ++ri)
            ax[q][ri] = *(const bf16x8*)(xb + ((q*2 + ri)*32 + bh*16 + row)*32 + kg*8);

    bf16x8 wpos[4][2], wneg[4][2];
    #pragma unroll
    for (int p = 0; p < 4; ++p)
        #pragma unroll
        for (int ri = 0; ri < 2; ++ri) {
            bf16x8 w = *(const bf16x8*)(wb + ((p*2 + ri)*32 + oh*16 + row)*32 + kg*8);
            wpos[p][ri] = w;
            i32x4 t = __builtin_bit_cast(i32x4, w);
            t ^= (int)0x80008000;
            wneg[p][ri] = __builtin_bit_cast(bf16x8, t);
        }

    f32x4 acc[4][2];
    #pragma unroll
    for (int c = 0; c < 4; ++c)
        #pragma unroll
        for (int ri = 0; ri < 2; ++ri)
            acc[c][ri] = (f32x4){0.f, 0.f, 0.f, 0.f};

    constexpr int PI_[4][4] = {{0,1,2,3},{1,0,3,2},{2,3,0,1},{3,2,1,0}};
    constexpr int SG_[4][4] = {{1,-1,-1,-1},{1,1,-1,1},{1,1,1,-1},{1,-1,1,1}};
    #pragma unroll
    for (int c = 0; c < 4; ++c)
        #pragma unroll
        for (int q = 0; q < 4; ++q) {
            const int  p   = PI_[c][q];
            const bool pos = SG_[c][q] > 0;
            bf16x8 wr_s = pos ? wpos[p][0] : wneg[p][0];
            bf16x8 wi_s = pos ? wpos[p][1] : wneg[p][1];
            bf16x8 wi_m = pos ? wneg[p][1] : wpos[p][1];
            acc[c][0] = __builtin_amdgcn_mfma_f32_16x16x32_bf16(ax[q][0], wr_s, acc[c][0], 0, 0, 0);
            acc[c][0] = __builtin_amdgcn_mfma_f32_16x16x32_bf16(ax[q][1], wi_m, acc[c][0], 0, 0, 0);
            acc[c][1] = __builtin_amdgcn_mfma_f32_16x16x32_bf16(ax[q][1], wr_s, acc[c][1], 0, 0, 0);
            acc[c][1] = __builtin_amdgcn_mfma_f32_16x16x32_bf16(ax[q][0], wi_s, acc[c][1], 0, 0, 0);
        }

    u32* __restrict__ dst = P + (size_t)bin * 4096;
    #pragma unroll
    for (int c = 0; c < 4; ++c)
        #pragma unroll
        for (int r = 0; r < 4; ++r) {
            int b_ = bh*16 + kg*4 + r;
            int o  = oh*16 + row;
            dst[c*1024 + b_*32 + o] = pk(make_float2(acc[c][0][r], acc[c][1][r]));
        }
}

// ---------------- inverse rfft2 via MFMA-DFT: reads P[bin][img] directly ----------------
__global__ __launch_bounds__(512, 4) void fft_inv_kernel(const u32* __restrict__ P,
                                                         float* __restrict__ out)
{
    __shared__ __align__(16) u16 mats[2][64*72];   // cos/sin(+2pi ab/64), symmetric
    __shared__ __align__(16) u16 wbuf[4][7168];    // per-image: ET (2x48x72) / T (2x64x56)

    const int tid  = threadIdx.x;
    const int lane = tid & 63;
    const int wid  = tid >> 6;
    const int slot = wid >> 1;
    const int half = wid & 1;
    const int ltid = (half << 6) | lane;
    const int a16  = lane & 15;
    const int q    = lane >> 4;

    const int bid = blockIdx.x;
    const int g   = (bid & 7) * 128 + (bid >> 3);  // bijective: 1024 = 8 x 128
    const int img = g * 4 + slot;                  // c*1024 + b*32 + oc
    const int c  = img >> 10;
    const int b  = (img >> 5) & 31;
    const int oc = img & 31;

    for (int t = tid; t < 4096; t += 512) {
        int a = t >> 6, bb = t & 63;
        float sn, cs;
        __sincosf(PI2 * (float)((a*bb) & 63) * (1.f/64.f), &sn, &cs);
        mats[0][a*72 + bb] = f2h(cs);
        mats[1][a*72 + bb] = f2h(sn);
    }

    // zero the garbage rows k=33..47 of this slot's ET (MFMA A-rows must be 0, not stale)
    {
        u16* ETre = wbuf[slot];
        u16* ETim = wbuf[slot] + 48*72;
        for (int j = 33*72 + ltid; j < 48*72; j += 128) {
            ETre[j] = 0;
            ETim[j] = 0;
        }
    }
    // block-wide gather: for each bin, 4 consecutive u32 (the block's 4 images)
    for (int e = tid; e < NBIN*4; e += 512) {
        int bin = e >> 2, sl = e & 3;
        u32 v = P[(size_t)bin * 4096 + g*4 + sl];
        float2 f = upk(v);
        int hf = bin / 33, k = bin - hf*33;
        u16* ETre = wbuf[sl];
        u16* ETim = wbuf[sl] + 48*72;
        ETre[k*72 + hf] = f2h(f.x);
        ETim[k*72 + hf] = f2h(f.y);
    }
    __syncthreads();

    // preload this wave's E^T A-fragments (mt = 2*half + mtl, valid mt < 3)
    u16* ETre = wbuf[slot];
    u16* ETim = wbuf[slot] + 48*72;
    f16x8 ere[2][2], eim[2][2];
    #pragma unroll
    for (int mtl = 0; mtl < 2; ++mtl) {
        const int mt = 2*half + mtl;
        if (mt < 3) {
            #pragma unroll
            for (int ks = 0; ks < 2; ++ks) {
                ere[mtl][ks] = *(const f16x8*)&ETre[(16*mt + a16)*72 + ks*32 + q*8];
                eim[mtl][ks] = *(const f16x8*)&ETim[(16*mt + a16)*72 + ks*32 + q*8];
            }
        }
    }
    __syncthreads();

    // step1: T_re^T = Ere*C - Eim*S ; T_im^T = Ere*S + Eim*C; D-layout writes T[h][m]
    u16* Tre = wbuf[slot];             // [64][56]
    u16* Tim = wbuf[slot] + 64*56;
    #pragma unroll
    for (int mtl = 0; mtl < 2; ++mtl) {
        const int mt = 2*half + mtl;
        if (mt < 3) {
            #pragma unroll
            for (int nt = 0; nt < 4; ++nt) {
                f32x4 tre = (f32x4){0,0,0,0}, tim = (f32x4){0,0,0,0};
                #pragma unroll
                for (int ks = 0; ks < 2; ++ks) {
                    const int rb = (16*nt + a16)*72 + ks*32 + q*8;
                    f16x8 cf = *(const f16x8*)&mats[0][rb];
                    f16x8 sf = *(const f16x8*)&mats[1][rb];
                    tre = __builtin_amdgcn_mfma_f32_16x16x32_f16(ere[mtl][ks], cf, tre, 0, 0, 0);
                    tre = __builtin_amdgcn_mfma_f32_16x16x32_f16(eim[mtl][ks], negh(sf), tre, 0, 0, 0);
                    tim = __builtin_amdgcn_mfma_f32_16x16x32_f16(ere[mtl][ks], sf, tim, 0, 0, 0);
                    tim = __builtin_amdgcn_mfma_f32_16x16x32_f16(eim[mtl][ks], cf, tim, 0, 0, 0);
                }
                const int m0 = 16*mt + 4*q;        // row = m, col = h
                u16x4 r4, i4;
                #pragma unroll
                for (int r = 0; r < 4; ++r) {
                    int m = m0 + r;
                    float s = (m == 0 || m == 32) ? (1.f/4096.f) : (2.f/4096.f);
                    r4[r] = (m < 33) ? f2h(tre[r] * s) : (u16)0;
                    i4[r] = (m < 33) ? f2h(tim[r] * s) : (u16)0;
                }
                *(u16x4*)&Tre[(16*nt + a16)*56 + m0] = r4;
                *(u16x4*)&Tim[(16*nt + a16)*56 + m0] = i4;
            }
        }
    }
    __syncthreads();

    // step2: out[h][w] = sum_m Tre[h][m]*C[w][m] - Tim[h][m]*S[w][m]
    float* __restrict__ dst = out + ((size_t)b*128 + (size_t)c*32 + oc) * (FH*FW);
    #pragma unroll
    for (int mtl = 0; mtl < 2; ++mtl) {
        const int mt = 2*half + mtl;
        f16x8 tfr[2], tfi[2];
        #pragma unroll
        for (int ks = 0; ks < 2; ++ks) {
            const int mbase = ks*32 + q*8;
            if (mbase < 48) {
                tfr[ks] = *(const f16x8*)&Tre[(16*mt + a16)*56 + mbase];
                tfi[ks] = *(const f16x8*)&Tim[(16*mt + a16)*56 + mbase];
            } else {
                tfr[ks] = (f16x8){0,0,0,0,0,0,0,0};
                tfi[ks] = (f16x8){0,0,0,0,0,0,0,0};
            }
        }
        #pragma unroll
        for (int nt = 0; nt < 4; ++nt) {
            f32x4 acc = (f32x4){0,0,0,0};
            #pragma unroll
            for (int ks = 0; ks < 2; ++ks) {
                const int rb = (16*nt + a16)*72 + ks*32 + q*8;
                f16x8 cf = *(const f16x8*)&mats[0][rb];
                f16x8 sf = *(const f16x8*)&mats[1][rb];
                acc = __builtin_amdgcn_mfma_f32_16x16x32_f16(tfr[ks], cf, acc, 0, 0, 0);
                acc = __builtin_amdgcn_mfma_f32_16x16x32_f16(tfi[ks], negh(sf), acc, 0, 0, 0);
            }
            // col = w = 16nt+a16, row = h = 16mt+4q+r
            #pragma unroll
            for (int r = 0; r < 4; ++r)
                dst[(16*mt + 4*q + r)*64 + 16*nt + a16] = acc[r];
        }
    }
}

extern "C" void kernel_launch(void* const* d_in, const int* in_sizes, int n_in,
                              void* d_out, int out_size, void* d_ws, size_t ws_size,
                              hipStream_t stream)
{
    const float* x   = (const float*)d_in[0];
    const float* krw = (const float*)d_in[1];
    const float* krx = (const float*)d_in[2];
    const float* kry = (const float*)d_in[3];
    const float* krz = (const float*)d_in[4];
    const float* kiw = (const float*)d_in[5];
    const float* kix = (const float*)d_in[6];
    const float* kiy = (const float*)d_in[7];
    const float* kiz = (const float*)d_in[8];

    // ws regions (34.6 MB each): [XT] [WT] [Xs / P aliased]
    const size_t R = (size_t)NBIN * 8192 * sizeof(u16);   // 34.6 MB
    u16* XT = (u16*)d_ws;
    u16* WT = (u16*)((char*)d_ws + R);
    u32* Xs = (u32*)((char*)d_ws + 2*R);
    u32* P  = Xs;                                          // alias: Xs dead after xpose
    float* out = (float*)d_out;

    fwd_prep_kernel<<<dim3(1024 + 2112), 512, 0, stream>>>(x, Xs,
                                                           krw, krx, kry, krz,
                                                           kiw, kix, kiy, kiz, WT);
    xpose_x_kernel<<<dim3(128, NBIN/32), 256, 0, stream>>>(Xs, (u32*)XT);
    contract_kernel<<<dim3(NBIN), 256, 0, stream>>>(XT, WT, P);
    fft_inv_kernel<<<dim3(NIMG/4), 512, 0, stream>>>(P, out);
}